// Round 10
// baseline (626.432 us; speedup 1.0000x reference)
//
#include <hip/hip_runtime.h>

typedef __attribute__((ext_vector_type(8))) short  short8v;
typedef __attribute__((ext_vector_type(4))) float  float4v;

#define BDIM 1024

// bf16 weights pre-arranged in MFMA B-fragment order, 1KB chunks:
// ushort offset = (((p*8+kb)*16 + c16)*2 + s)*512 + lane*8
// lane l holds 8 bf16: B_p[c16*16 + (l&15)][kb*64 + s*32 + (l>>4)*8 + j]
// B_p = [W_p | U_p] K-concatenated (512 wide). (verified: rounds 4/7/8/9)
__device__ ushort g_w[3 * 8 * 16 * 2 * 64 * 8];   // 768 KB

__device__ __forceinline__ ushort f2bf(float f) {
  unsigned u = __float_as_uint(f);
  u += 0x7fffu + ((u >> 16) & 1u);          // round-to-nearest-even
  return (ushort)(u >> 16);
}
__device__ __forceinline__ float bf2f(ushort s) {
  return __uint_as_float(((unsigned)s) << 16);
}

__global__ __launch_bounds__(256) void conv_w(
    const float* __restrict__ Wz, const float* __restrict__ Uz,
    const float* __restrict__ Wa, const float* __restrict__ Ua,
    const float* __restrict__ Wh, const float* __restrict__ Uh)
{
  int tid = blockIdx.x * 256 + threadIdx.x;   // 49152 total = one lane-slot each
  int p   = tid >> 14;
  int kb  = (tid >> 11) & 7;
  int c16 = (tid >> 7) & 15;
  int s   = (tid >> 6) & 1;
  int l   = tid & 63;
  const float* W = (p == 0) ? Wz : (p == 1) ? Wa : Wh;
  const float* U = (p == 0) ? Uz : (p == 1) ? Ua : Uh;
  int col = c16 * 16 + (l & 15);              // output column (weight row)
  int k0  = kb * 64 + s * 32 + ((l >> 4) << 3);  // 8-aligned, never straddles 256
  const float* src = (k0 < 256) ? (W + col * 256 + k0) : (U + col * 256 + (k0 - 256));
  uint pk[4];
#pragma unroll
  for (int jj = 0; jj < 4; ++jj) {
    float v0 = src[jj * 2], v1 = src[jj * 2 + 1];
    pk[jj] = (uint)f2bf(v0) | ((uint)f2bf(v1) << 16);
  }
  *reinterpret_cast<uint4*>(&g_w[(size_t)tid * 8]) = make_uint4(pk[0], pk[1], pk[2], pk[3]);
}

// Round 10: 16 waves x 16 cols/wave. AGPR halves to 32 (accZ16+accA16), so
// arch state (~80) + AGPR fits the 128-total budget of 4 waves/EU with NO
// spills (r9 spilled ~200B/thread: FETCH/WRITE +100/+135MB over floor).
// Merged z+attn K-loop (shared afr), distance-2 B-prefetch, barrier-free.
__global__ __launch_bounds__(BDIM, 4)
void gru_fused(
    const float* __restrict__ x,  const float* __restrict__ hp,
    const float* __restrict__ bz, const float* __restrict__ va,
    const float* __restrict__ bh, float* __restrict__ out)
{
  // A-tile: [64 rows][512 K] bf16, 16B-chunk XOR swizzle  (64 KB)
  __shared__ __align__(16) ushort sA[64 * 512];
  __shared__ __align__(16) float  sRed[2][64 * 16];  // softmax cross-wave scratch (8 KB)

  const int tid  = threadIdx.x;
  const int wv   = tid >> 6;       // wave 0..15, owns cols [wv*16, wv*16+16)
  const int lane = tid & 63;
  const int g4   = lane >> 4;
  const int l15  = lane & 15;
  const int sxor = l15 & 7;
  const int col  = (wv << 4) + l15;
  const int rowBlk = blockIdx.x << 6;

  // B-fragment stream bases (one 1KB chunk per wave per stream per K=32 step)
  const ushort* wbase = g_w + (size_t)(wv << 10) + (size_t)(lane << 3);
  const ushort* pZ = wbase;
  const ushort* pA = wbase + 131072;
  const ushort* pH = wbase + 262144;
  auto ld = [&](const ushort* px, int t) -> short8v {
    return *reinterpret_cast<const short8v*>(px + ((size_t)(t >> 1) << 13) * 2 + ((size_t)(t & 1) << 9));
  };

  // prologue: steps 0 and 1 of both merged streams in flight under A-stage
  short8v bZ0 = ld(pZ, 0), bA0 = ld(pA, 0);
  short8v bZ1 = ld(pZ, 1), bA1 = ld(pA, 1);
  short8v bH0, bH1;

  { // stage A = [x | h] as bf16, swizzled
    const float4* xq = reinterpret_cast<const float4*>(x)  + (size_t)rowBlk * 64;
    const float4* hq = reinterpret_cast<const float4*>(hp) + (size_t)rowBlk * 64;
#pragma unroll
    for (int i = 0; i < 8; ++i) {
      int q   = tid + i * BDIM;        // 0..8191 quad index
      int row = q >> 7;
      int qc  = q & 127;
      float4 v = (qc < 64) ? xq[row * 64 + qc] : hq[row * 64 + qc - 64];
      int kE  = qc << 2;
      int swz = (kE >> 3) ^ (row & 7);
      ushort4 pk4;
      pk4.x = f2bf(v.x); pk4.y = f2bf(v.y); pk4.z = f2bf(v.z); pk4.w = f2bf(v.w);
      *reinterpret_cast<ushort4*>((char*)sA + (row << 10) + (swz << 4) + ((kE & 7) << 1)) = pk4;
    }
  }
  __syncthreads();   // sA ready; read-only until the attention epilogue

  float4v accZ[4], accA[4];
#pragma unroll
  for (int m = 0; m < 4; ++m) {
    accZ[m] = (float4v){0.f, 0.f, 0.f, 0.f};
    accA[m] = (float4v){0.f, 0.f, 0.f, 0.f};
  }

  // ---- merged K-loop (16 steps of K=32): z-GEMM + attn-GEMM share afr ----
  for (int kb = 0; kb < 8; ++kb) {
    short8v afr[4];
    // s = 0
#pragma unroll
    for (int m = 0; m < 4; ++m) {
      int swz = (kb * 8 + g4) ^ sxor;
      afr[m] = *reinterpret_cast<const short8v*>(
          (const char*)sA + ((m * 16 + l15) << 10) + (swz << 4));
    }
#pragma unroll
    for (int m = 0; m < 4; ++m) {
      accZ[m] = __builtin_amdgcn_mfma_f32_16x16x32_bf16(afr[m], bZ0, accZ[m], 0, 0, 0);
      accA[m] = __builtin_amdgcn_mfma_f32_16x16x32_bf16(afr[m], bA0, accA[m], 0, 0, 0);
    }
    if (kb < 7) { bZ0 = ld(pZ, 2 * kb + 2); bA0 = ld(pA, 2 * kb + 2); }
    else        { bH0 = ld(pH, 0); }
    // s = 1
#pragma unroll
    for (int m = 0; m < 4; ++m) {
      int swz = (kb * 8 + 4 + g4) ^ sxor;
      afr[m] = *reinterpret_cast<const short8v*>(
          (const char*)sA + ((m * 16 + l15) << 10) + (swz << 4));
    }
#pragma unroll
    for (int m = 0; m < 4; ++m) {
      accZ[m] = __builtin_amdgcn_mfma_f32_16x16x32_bf16(afr[m], bZ1, accZ[m], 0, 0, 0);
      accA[m] = __builtin_amdgcn_mfma_f32_16x16x32_bf16(afr[m], bA1, accA[m], 0, 0, 0);
    }
    if (kb < 7) { bZ1 = ld(pZ, 2 * kb + 3); bA1 = ld(pA, 2 * kb + 3); }
    else        { bH1 = ld(pH, 1); }
  }

  // ---- z epilogue: z = sigmoid(pre + b_z), bf16-packed ----
  uint zp[4][2];
  {
    float b = bz[col];
#pragma unroll
    for (int m = 0; m < 4; ++m)
#pragma unroll
      for (int jj = 0; jj < 2; ++jj) {
        float z0 = 1.f / (1.f + __expf(-(accZ[m][2 * jj]     + b)));
        float z1 = 1.f / (1.f + __expf(-(accZ[m][2 * jj + 1] + b)));
        zp[m][jj] = (uint)f2bf(z0) | ((uint)f2bf(z1) << 16);
      }
  }

  // ---- attention epilogue: tanh*v_a, row-softmax, attended -> sA ----
  uint hvp[4][2];
  {
    float vav = va[col];
#pragma unroll
    for (int m = 0; m < 4; ++m)
#pragma unroll
      for (int j = 0; j < 4; ++j) {
        float s = accA[m][j];
        float t = 1.f - 2.f / (__expf(2.f * s) + 1.f);
        accA[m][j] = t * vav;
      }
    float mx[4][4];
#pragma unroll
    for (int m = 0; m < 4; ++m)
#pragma unroll
      for (int j = 0; j < 4; ++j) {
        float v = accA[m][j];
        v = fmaxf(v, __shfl_xor(v, 1));
        v = fmaxf(v, __shfl_xor(v, 2));
        v = fmaxf(v, __shfl_xor(v, 4));
        v = fmaxf(v, __shfl_xor(v, 8));
        mx[m][j] = v;
      }
    if (l15 == 0) {
#pragma unroll
      for (int m = 0; m < 4; ++m)
#pragma unroll
        for (int j = 0; j < 4; ++j)
          sRed[0][((m * 16 + g4 * 4 + j) << 4) + wv] = mx[m][j];
    }
    __syncthreads();
    float rmax[4][4];
#pragma unroll
    for (int m = 0; m < 4; ++m)
#pragma unroll
      for (int j = 0; j < 4; ++j) {
        int row = m * 16 + g4 * 4 + j;
        const float4* pr = reinterpret_cast<const float4*>(&sRed[0][row << 4]);
        float4 a = pr[0], b = pr[1], c = pr[2], d = pr[3];
        float v01 = fmaxf(fmaxf(a.x, a.y), fmaxf(a.z, a.w));
        float v23 = fmaxf(fmaxf(b.x, b.y), fmaxf(b.z, b.w));
        float v45 = fmaxf(fmaxf(c.x, c.y), fmaxf(c.z, c.w));
        float v67 = fmaxf(fmaxf(d.x, d.y), fmaxf(d.z, d.w));
        rmax[m][j] = fmaxf(fmaxf(v01, v23), fmaxf(v45, v67));
      }
#pragma unroll
    for (int m = 0; m < 4; ++m)
#pragma unroll
      for (int j = 0; j < 4; ++j) {
        float e = __expf(accA[m][j] - rmax[m][j]);
        accA[m][j] = e;
        float sm = e;
        sm += __shfl_xor(sm, 1);
        sm += __shfl_xor(sm, 2);
        sm += __shfl_xor(sm, 4);
        sm += __shfl_xor(sm, 8);
        if (l15 == 0) sRed[1][((m * 16 + g4 * 4 + j) << 4) + wv] = sm;
      }
    // capture h (own output positions, raw bf16) BEFORE overwrite
#pragma unroll
    for (int m = 0; m < 4; ++m)
#pragma unroll
      for (int jj = 0; jj < 2; ++jj) {
        int row0 = m * 16 + g4 * 4 + 2 * jj;
        int row1 = row0 + 1;
        int ch   = 32 + (wv << 1) + (l15 >> 3);
        int cs0  = ch ^ (row0 & 7);
        int cs1  = ch ^ (row1 & 7);
        uint h0 = sA[(row0 << 9) + (cs0 << 3) + sxor];
        uint h1 = sA[(row1 << 9) + (cs1 << 3) + sxor];
        hvp[m][jj] = h0 | (h1 << 16);
      }
    __syncthreads();   // all h captured; sum scratch ready
#pragma unroll
    for (int m = 0; m < 4; ++m)
#pragma unroll
      for (int j = 0; j < 4; ++j) {
        int row = m * 16 + g4 * 4 + j;
        const float4* pr = reinterpret_cast<const float4*>(&sRed[1][row << 4]);
        float4 a = pr[0], b = pr[1], c = pr[2], d = pr[3];
        float s = ((a.x + a.y) + (a.z + a.w)) + ((b.x + b.y) + (b.z + b.w))
                + ((c.x + c.y) + (c.z + c.w)) + ((d.x + d.y) + (d.z + d.w));
        float inv = 1.f / s;
        uint hw = hvp[m][j >> 1];
        float hval = bf2f((ushort)((j & 1) ? (hw >> 16) : (hw & 0xffffu)));
        float at = accA[m][j] * inv * hval;
        int ch = 32 + (wv << 1) + (l15 >> 3);
        int cs = ch ^ (row & 7);
        sA[(row << 9) + (cs << 3) + sxor] = f2bf(at);
      }
    __syncthreads();   // attended in sA; safe for candidate K-loop
  }

  // ---- candidate K-loop: h~ GEMM ----
  float4v accH[4];
#pragma unroll
  for (int m = 0; m < 4; ++m)
    accH[m] = (float4v){0.f, 0.f, 0.f, 0.f};
  for (int kb = 0; kb < 8; ++kb) {
    short8v afr[4];
#pragma unroll
    for (int m = 0; m < 4; ++m) {
      int swz = (kb * 8 + g4) ^ sxor;
      afr[m] = *reinterpret_cast<const short8v*>(
          (const char*)sA + ((m * 16 + l15) << 10) + (swz << 4));
    }
#pragma unroll
    for (int m = 0; m < 4; ++m)
      accH[m] = __builtin_amdgcn_mfma_f32_16x16x32_bf16(afr[m], bH0, accH[m], 0, 0, 0);
    if (kb < 7) bH0 = ld(pH, 2 * kb + 2);
#pragma unroll
    for (int m = 0; m < 4; ++m) {
      int swz = (kb * 8 + 4 + g4) ^ sxor;
      afr[m] = *reinterpret_cast<const short8v*>(
          (const char*)sA + ((m * 16 + l15) << 10) + (swz << 4));
    }
#pragma unroll
    for (int m = 0; m < 4; ++m)
      accH[m] = __builtin_amdgcn_mfma_f32_16x16x32_bf16(afr[m], bH1, accH[m], 0, 0, 0);
    if (kb < 7) bH1 = ld(pH, 2 * kb + 3);
  }

  // ---- final: h~ = tanh(pre + b_h); h_t = (1-z)h + z h~ ----
  {
    float b = bh[col];
#pragma unroll
    for (int m = 0; m < 4; ++m)
#pragma unroll
      for (int j = 0; j < 4; ++j) {
        float s  = accH[m][j] + b;
        float ht = 1.f - 2.f / (__expf(2.f * s) + 1.f);
        uint zw  = zp[m][j >> 1];
        float z  = bf2f((ushort)((j & 1) ? (zw >> 16) : (zw & 0xffffu)));
        uint hw  = hvp[m][j >> 1];
        float h0 = bf2f((ushort)((j & 1) ? (hw >> 16) : (hw & 0xffffu)));
        float res = (1.f - z) * h0 + z * ht;
        int row = m * 16 + g4 * 4 + j;
        out[(size_t)(rowBlk + row) * 256 + col] = res;
      }
  }
}

extern "C" void kernel_launch(void* const* d_in, const int* in_sizes, int n_in,
                              void* d_out, int out_size, void* d_ws, size_t ws_size,
                              hipStream_t stream)
{
  const float* x  = (const float*)d_in[0];
  const float* hp = (const float*)d_in[1];
  const float* Wz = (const float*)d_in[2];
  const float* Uz = (const float*)d_in[3];
  const float* bz = (const float*)d_in[4];
  const float* Wa = (const float*)d_in[5];
  const float* Ua = (const float*)d_in[6];
  const float* va = (const float*)d_in[7];
  const float* Wh = (const float*)d_in[8];
  const float* Uh = (const float*)d_in[9];
  const float* bh = (const float*)d_in[10];
  float* out = (float*)d_out;

  conv_w<<<dim3(192), dim3(256), 0, stream>>>(Wz, Uz, Wa, Ua, Wh, Uh);
  gru_fused<<<dim3(1024), dim3(BDIM), 0, stream>>>(x, hp, bz, va, bh, out);
}